// Round 23
// baseline (144.831 us; speedup 1.0000x reference)
//
#include <hip/hip_runtime.h>
#include <hip/hip_bf16.h>
#include <stdint.h>

typedef unsigned short ushort_t;
typedef __attribute__((ext_vector_type(8))) short short8;
typedef __attribute__((ext_vector_type(4))) short short4v;
typedef __attribute__((ext_vector_type(4))) unsigned short ushort4v;
typedef __attribute__((ext_vector_type(4))) float f32x4;

#define L_SEQ   2048
#define BATCH   8
#define M_ROWS  16384          // BATCH*L_SEQ
#define EPSV    1e-5f
#define BC_NB   128            // 64 m-tiles(256) x 2 n-tiles(128)
#define DTR_NB  1024           // 16 rows per block
#define ZL_NB   256            // 8 cols per block

__device__ __forceinline__ float bf2f(ushort_t u){
  union { uint32_t i; float f; } v; v.i = ((uint32_t)u) << 16; return v.f;
}
__device__ __forceinline__ ushort_t f2bf(float f){
  union { float f; uint32_t i; } v; v.f = f;
  uint32_t r = v.i + 0x7fffu + ((v.i >> 16) & 1u);
  return (ushort_t)(r >> 16);
}

// ---------------- prep: xb, fp32 transposes, Afold bf16, w2tp bf16, yfin zero ----------------
__global__ __launch_bounds__(256)
void k_prep(const float* __restrict__ x, const float* __restrict__ w_proj,
            const float* __restrict__ b_proj, const float* __restrict__ w_in,
            const float* __restrict__ w_out, const float* __restrict__ w_head,
            ushort_t* __restrict__ xb, float* __restrict__ wzT,
            float* __restrict__ wot, float* __restrict__ wht,
            float* __restrict__ wpT, ushort_t* __restrict__ Afold,
            ushort_t* __restrict__ w2tp, float* __restrict__ yfin){
  __shared__ float tile[64][65];
  int bx = blockIdx.x, tid = threadIdx.x;
  if (bx < 4096){                          // x -> bf16
    int i = bx * 256 + tid;
    xb[i] = f2bf(x[i]);
    return;
  }
  bx -= 4096;
  if (bx < 512 + 512 + 16 + 16){
    const float* src; float* dstf;
    int R, C, colOff, j0, k0; bool isWpT = false;
    if (bx < 512){               src = w_in;   dstf = wzT; R = 1024; C = 4384; colOff = 0; j0 = (bx % 32) * 64; k0 = (bx / 32) * 64; }
    else if ((bx -= 512) < 512){ src = w_out;  dstf = wot; R = 2048; C = 1024; colOff = 0; j0 = (bx % 16) * 64; k0 = (bx / 16) * 64; }
    else if ((bx -= 512) < 16){  src = w_head; dstf = wht; R = 1024; C = 64;   colOff = 0; j0 = 0;             k0 = bx * 64; }
    else { bx -= 16;             src = w_proj; dstf = wpT; R = 64;   C = 1024; colOff = 0; j0 = bx * 64;       k0 = 0; isWpT = true; }
    int tx = tid & 63, ty = tid >> 6;
    #pragma unroll
    for (int i = 0; i < 16; ++i){
      int kk = ty * 16 + i;
      if (!isWpT || (k0 + kk) < 64)
        tile[kk][tx] = src[(size_t)(k0 + kk) * C + colOff + j0 + tx];
    }
    __syncthreads();
    #pragma unroll
    for (int i = 0; i < 16; ++i){
      int jj = ty * 16 + i;
      if (isWpT) dstf[(size_t)(j0 + jj) * 64 + tx] = tile[tx][jj];
      else       dstf[(size_t)(j0 + jj) * R + k0 + tx] = tile[tx][jj];
    }
    return;
  }
  bx -= 1056;
  if (bx < 512){                           // Afold[128][1024] bf16
    int i = bx * 256 + tid;
    int row = i >> 10, col = i & 1023;
    float v = (row < 64) ? w_proj[(size_t)row * 1024 + col]
            : (row == 64) ? b_proj[col] : 0.f;
    Afold[i] = f2bf(v);
    return;
  }
  bx -= 512;
  if (bx < 608){                           // w2tp[2432][1024] bf16
    int j0 = (bx % 38) * 64;
    int k0 = (bx / 38) * 64;
    int tx = tid & 63, ty = tid >> 6;
    #pragma unroll
    for (int i = 0; i < 16; ++i){
      int kk = ty * 16 + i;
      int j = j0 + tx;
      tile[kk][tx] = (j < 2304) ? w_in[(size_t)(k0 + kk) * 4384 + 2048 + j] : 0.f;
    }
    __syncthreads();
    #pragma unroll
    for (int i = 0; i < 16; ++i){
      int jj = ty * 16 + i;
      w2tp[(size_t)(j0 + jj) * 1024 + k0 + tx] = f2bf(tile[tx][jj]);
    }
    return;
  }
  bx -= 608;
  yfin[bx * 256 + tid] = 0.f;              // 64 blocks: zero yfin (16384 floats)
}

// ---------------- async global->LDS ----------------
__device__ __forceinline__ void gload16(const void* g, void* l){
  __builtin_amdgcn_global_load_lds((const __attribute__((address_space(1))) void*)g,
                                   (__attribute__((address_space(3))) void*)l, 16, 0, 0);
}

// ---------------- MFMA fold GEMM (19) + u_last (32) + dt fold (32) ----------------
__global__ __launch_bounds__(256)
void k_foldg(const ushort_t* __restrict__ Afold, const ushort_t* __restrict__ w2tp,
             ushort_t* __restrict__ Wcb, float* __restrict__ bc,
             const ushort_t* __restrict__ xb, const float* __restrict__ w_proj,
             const float* __restrict__ b_proj, float* __restrict__ ul,
             const float* __restrict__ wpT, const float* __restrict__ w_in,
             float* __restrict__ WdtT, float* __restrict__ bcdt){
  __shared__ ushort_t tA[128 * 32];
  __shared__ ushort_t tB[128 * 32];
  __shared__ float redf[4][64];
  const int bid = blockIdx.x;
  const int tid = threadIdx.x;
  const int lane = tid & 63;
  const int wave = tid >> 6;

  if (bid >= 51){
    int h = bid - 51;
    int a = tid & 63, q = tid >> 6;
    const float* wcol = w_in + 4352 + h;
    float acc = 0.f;
    const int d0 = q * 256;
    for (int d = d0; d < d0 + 256; ++d)
      acc += wpT[(size_t)d * 64 + a] * wcol[(size_t)d * 4384];
    redf[q][a] = acc;
    __syncthreads();
    if (q == 0){
      WdtT[h * 64 + a] = redf[0][a] + redf[1][a] + redf[2][a] + redf[3][a];
      float bacc = 0.f;
      #pragma unroll 4
      for (int i = 0; i < 16; ++i){
        int d = a + 64 * i;
        bacc += b_proj[d] * wcol[(size_t)d * 4384];
      }
      for (int s = 32; s; s >>= 1) bacc += __shfl_down(bacc, s, 64);
      if (a == 0) bcdt[h] = bacc;
    }
    return;
  }

  if (bid >= 19){
    int i = (bid - 19) * 256 + tid;
    int b = i >> 10, d = i & 1023;
    float acc = b_proj[d];
    const ushort_t* xrow = xb + ((size_t)(b * 2048 + 2047)) * 64;
    #pragma unroll 8
    for (int k = 0; k < 64; ++k)
      acc += bf2f(xrow[k]) * w_proj[(size_t)k * 1024 + d];
    ul[b * 1024 + d] = acc;
    return;
  }

  const int n0 = bid * 128;
  const int wr = wave >> 1, wc = wave & 1;
  const int l15 = lane & 15, l4 = lane >> 4;
  const int srow  = lane >> 2;
  const int skoff = (lane & 3) * 8;

  f32x4 acc[4][4];
  #pragma unroll
  for (int m = 0; m < 4; ++m)
    #pragma unroll
    for (int n = 0; n < 4; ++n)
      #pragma unroll
      for (int r = 0; r < 4; ++r) acc[m][n][r] = 0.f;

  for (int k0 = 0; k0 < 1024; k0 += 32){
    #pragma unroll
    for (int r = 0; r < 2; ++r){
      int chunk = r * 4 + wave;
      int rr = chunk * 16 + srow;
      gload16(Afold + (size_t)rr * 1024 + k0 + skoff, &tA[chunk * 512]);
      gload16(w2tp  + (size_t)(n0 + rr) * 1024 + k0 + skoff, &tB[chunk * 512]);
    }
    __syncthreads();
    short8 af[4], bfv[4];
    #pragma unroll
    for (int m = 0; m < 4; ++m)
      af[m] = *(const short8*)&tA[(wr * 64 + m * 16 + l15) * 32 + l4 * 8];
    #pragma unroll
    for (int n = 0; n < 4; ++n)
      bfv[n] = *(const short8*)&tB[(wc * 64 + n * 16 + l15) * 32 + l4 * 8];
    #pragma unroll
    for (int m = 0; m < 4; ++m)
      #pragma unroll
      for (int n = 0; n < 4; ++n)
        acc[m][n] = __builtin_amdgcn_mfma_f32_16x16x32_bf16(af[m], bfv[n], acc[m][n], 0, 0, 0);
    __syncthreads();
  }
  #pragma unroll
  for (int n = 0; n < 4; ++n){
    int col = n0 + wc * 64 + n * 16 + l15;
    #pragma unroll
    for (int m = 0; m < 4; ++m){
      int rowb = wr * 64 + m * 16 + l4 * 4;
      #pragma unroll
      for (int r = 0; r < 4; ++r){
        int row = rowb + r;
        if (row < 64)       Wcb[(size_t)col * 64 + row] = f2bf(acc[m][n][r]);
        else if (row == 64) bc[col] = acc[m][n][r];
      }
    }
  }
}

// ---------------- BC cols GEMM (256x128 tiles) + dt_raw + z_last ----------------
__global__ __launch_bounds__(512)
void k_gemmBC(const ushort_t* __restrict__ A, const ushort_t* __restrict__ Wcb,
              const float* __restrict__ bc, ushort_t* __restrict__ CBC,
              const float* __restrict__ WdtT, const float* __restrict__ bcdt,
              float* __restrict__ dtr, const float* __restrict__ ul,
              const float* __restrict__ wzT, float* __restrict__ z_last){
  __shared__ ushort_t lds[24576];
  const int bid = blockIdx.x;
  const int tid = threadIdx.x;
  const int lane = tid & 63;
  const int wave = tid >> 6;

  if (bid >= BC_NB + DTR_NB){
    int col = (bid - BC_NB - DTR_NB) * 8 + wave;
    float acc[8] = {0.f, 0.f, 0.f, 0.f, 0.f, 0.f, 0.f, 0.f};
    const float* wp = wzT + (size_t)col * 1024;
    #pragma unroll 4
    for (int i = 0; i < 16; ++i){
      int k = i * 64 + lane;
      float w = wp[k];
      #pragma unroll
      for (int b = 0; b < 8; ++b)
        acc[b] += ul[b * 1024 + k] * w;
    }
    #pragma unroll
    for (int b = 0; b < 8; ++b){
      float v = acc[b];
      for (int s = 32; s; s >>= 1) v += __shfl_down(v, s, 64);
      if (lane == 0) z_last[b * 2048 + col] = v;
    }
    return;
  }

  if (bid >= BC_NB){
    int r = tid >> 5, h = tid & 31;
    size_t m = (size_t)(bid - BC_NB) * 16 + r;
    const ushort_t* xrow = A + m * 64;
    const float* wrow = WdtT + h * 64;
    float acc = bcdt[h];
    #pragma unroll 8
    for (int k = 0; k < 64; ++k)
      acc += bf2f(xrow[k]) * wrow[k];
    dtr[m * 32 + h] = acc;
    return;
  }

  const int cpx = BC_NB >> 3;
  const int swz = (bid & 7) * cpx + (bid >> 3);
  const int m0 = (swz >> 1) * 256, n0 = (swz & 1) * 128;
  const int l15 = lane & 15, l4 = lane >> 4;

  #pragma unroll
  for (int i = 0; i < 4; ++i){
    int idx = i * 512 + tid;
    int row = idx >> 3, c16 = idx & 7;
    int scol = (c16 * 8) ^ ((row & 7) << 3);
    gload16(A + (size_t)(m0 + row) * 64 + scol, &lds[idx * 8]);
  }
  #pragma unroll
  for (int i = 0; i < 2; ++i){
    int idx = i * 512 + tid;
    int row = idx >> 3, c16 = idx & 7;
    int scol = (c16 * 8) ^ ((row & 7) << 3);
    gload16(Wcb + (size_t)(2048 + n0 + row) * 64 + scol, &lds[16384 + idx * 8]);
  }
  __syncthreads();

  f32x4 acc[2][8];
  #pragma unroll
  for (int m = 0; m < 2; ++m)
    #pragma unroll
    for (int n = 0; n < 8; ++n)
      #pragma unroll
      for (int r = 0; r < 4; ++r) acc[m][n][r] = 0.f;

  #pragma unroll
  for (int kk = 0; kk < 2; ++kk){
    short8 af[2], bfv[8];
    #pragma unroll
    for (int m = 0; m < 2; ++m){
      int row = wave * 32 + m * 16 + l15;
      int e = (kk * 32 + l4 * 8) ^ ((row & 7) << 3);
      af[m] = *(const short8*)&lds[row * 64 + e];
    }
    #pragma unroll
    for (int n = 0; n < 8; ++n){
      int row = n * 16 + l15;
      int e = (kk * 32 + l4 * 8) ^ ((row & 7) << 3);
      bfv[n] = *(const short8*)&lds[16384 + row * 64 + e];
    }
    #pragma unroll
    for (int m = 0; m < 2; ++m)
      #pragma unroll
      for (int n = 0; n < 8; ++n)
        acc[m][n] = __builtin_amdgcn_mfma_f32_16x16x32_bf16(af[m], bfv[n], acc[m][n], 0, 0, 0);
  }
  __syncthreads();

  #pragma unroll
  for (int half = 0; half < 2; ++half){
    if ((wave >> 2) == half){
      int wl = wave & 3;
      #pragma unroll
      for (int n = 0; n < 8; ++n){
        int col = n * 16 + l15;
        float bv = bc[2048 + n0 + col];
        #pragma unroll
        for (int m = 0; m < 2; ++m){
          #pragma unroll
          for (int r = 0; r < 4; ++r){
            int lr = wl * 32 + m * 16 + l4 * 4 + r;
            lds[lr * 128 + (col ^ ((lr & 7) << 3))] = f2bf(acc[m][n][r] + bv);
          }
        }
      }
    }
    __syncthreads();
    #pragma unroll
    for (int p = 0; p < 4; ++p){
      int gr = p * 32 + (tid >> 4);
      int cg = (tid & 15) * 8;
      short8 v = *(const short8*)&lds[gr * 128 + (cg ^ ((gr & 7) << 3))];
      *(short8*)&CBC[(size_t)(m0 + half * 128 + gr) * 256 + n0 + cg] = v;
    }
    __syncthreads();
  }
}

// ---------------- fused conv(B,C)+SiLU+gdot: g[b,t] ----------------
__global__ __launch_bounds__(256)
void k_bcg2(const ushort_t* __restrict__ xbcBC, const float* __restrict__ conv_w,
            const float* __restrict__ conv_b, float* __restrict__ g){
  __shared__ float csh[128];
  __shared__ float wsh[128][4];
  __shared__ float bsh[128];
  const int b = blockIdx.y;
  const int t0 = blockIdx.x * 32;
  const int tid = threadIdx.x;
  const size_t rowb = (size_t)b * 2048;

  if (tid < 128){
    int cB = 2048 + tid;
    f32x4 wb = *(const f32x4*)&conv_w[cB * 4];
    #pragma unroll
    for (int k = 0; k < 4; ++k) wsh[tid][k] = wb[k];
    bsh[tid] = conv_b[cB];
    int c = 2176 + tid;
    f32x4 w4 = *(const f32x4*)&conv_w[c * 4];
    float a = conv_b[c];
    #pragma unroll
    for (int k = 0; k < 4; ++k)
      a += bf2f(xbcBC[(rowb + 2044 + k) * 256 + 128 + tid]) * w4[k];
    csh[tid] = a / (1.f + __expf(-a));
  }
  __syncthreads();

  const int t = t0 + (tid >> 3);
  const int lg = tid & 7;
  const int cb0 = lg * 16;
  short8 v0[4], v1[4];
  #pragma unroll
  for (int k = 0; k < 4; ++k){
    int tt = t - 3 + k;
    if (tt >= 0){
      v0[k] = *(const short8*)&xbcBC[(rowb + tt) * 256 + cb0];
      v1[k] = *(const short8*)&xbcBC[(rowb + tt) * 256 + cb0 + 8];
    } else {
      short8 z = {0,0,0,0,0,0,0,0}; v0[k] = z; v1[k] = z;
    }
  }
  float gacc = 0.f;
  #pragma unroll
  for (int j = 0; j < 8; ++j){
    int c = cb0 + j;
    float a = bsh[c];
    #pragma unroll
    for (int k = 0; k < 4; ++k) a += bf2f((ushort_t)v0[k][j]) * wsh[c][k];
    gacc += (a / (1.f + __expf(-a))) * csh[c];
  }
  #pragma unroll
  for (int j = 0; j < 8; ++j){
    int c = cb0 + 8 + j;
    float a = bsh[c];
    #pragma unroll
    for (int k = 0; k < 4; ++k) a += bf2f((ushort_t)v1[k][j]) * wsh[c][k];
    gacc += (a / (1.f + __expf(-a))) * csh[c];
  }
  #pragma unroll
  for (int s = 4; s; s >>= 1) gacc += __shfl_down(gacc, s, 8);
  if (lg == 0) g[rowb + t] = gacc;
}

// ---------------- per-(b,h) suffix scan -> coeff ----------------
__global__ void k_coeff(const float* __restrict__ dt_raw, const float* __restrict__ dt_bias,
                        const float* __restrict__ A_log, const float* __restrict__ g,
                        float* __restrict__ coeffw){
  __shared__ float csum[256];
  int bh = blockIdx.x;
  int b = bh >> 5, h = bh & 31;
  float Ah = -__expf(A_log[h]);
  float bias = dt_bias[h];
  int tid = threadIdx.x;
  size_t base = (size_t)b * 2048;
  float d[8], dts[8];
  #pragma unroll
  for (int j = 0; j < 8; ++j){
    int t = tid * 8 + j;
    float x = dt_raw[(base + t) * 32 + h] + bias;
    float sp = (x > 20.f) ? x : log1pf(__expf(x));
    dts[j] = sp;
    d[j] = sp * Ah;
  }
  float cs = 0.f;
  #pragma unroll
  for (int j = 0; j < 8; ++j) cs += d[j];
  csum[tid] = cs;
  __syncthreads();
  float suf = 0.f;
  for (int j = tid + 1; j < 256; ++j) suf += csum[j];
  float S = suf, outv[8];
  for (int j = 7; j >= 0; --j){ outv[j] = S; S += d[j]; }
  #pragma unroll
  for (int j = 0; j < 8; ++j){
    int t = tid * 8 + j;
    coeffw[(size_t)bh * 2048 + t] = __expf(outv[j]) * dts[j] * g[base + t];
  }
}

// ---------------- FUSED x-part: MFMA -> register conv+SiLU+coeff-sum -> yfin ----------------
// grid (16 n-blocks of 128 ch, 64 m-tiles of 256 t); 512 threads; 4 quarters of 64 t.
// History tile carried in registers across quarters (aa[0] = aa[4]).
__global__ __launch_bounds__(512)
void k_xsum(const ushort_t* __restrict__ xb, const ushort_t* __restrict__ Wcb,
            const float* __restrict__ bcv, const float* __restrict__ conv_w,
            const float* __restrict__ conv_b, const float* __restrict__ cfw,
            float* __restrict__ yfin, ushort_t* __restrict__ xhl){
  __shared__ char S[12288];
  ushort_t* Al = (ushort_t*)S;              // [80][64]  (10240 B)
  float*    Cl = (float*)(S + 10240);       // [2][256]  (2048 B)
  const int tid = threadIdx.x, lane = tid & 63, wave = tid >> 6;
  const int n0 = blockIdx.x * 128;
  const int mt = blockIdx.y;
  const int b = mt >> 3, t0 = (mt & 7) * 256;
  const int l15 = lane & 15, l4 = lane >> 4;

  // B-fragment + per-channel conv params in regs
  const int colw = wave * 16 + l15;
  const short8 bf0 = *(const short8*)&Wcb[(size_t)(n0 + colw) * 64 + l4 * 8];
  const short8 bf1 = *(const short8*)&Wcb[(size_t)(n0 + colw) * 64 + 32 + l4 * 8];
  const float bcw = bcv[n0 + colw];
  const f32x4 wcv = *(const f32x4*)&conv_w[(n0 + colw) * 4];
  const float cbw = conv_b[n0 + colw];
  const int hsel = (colw >> 6);             // head select within the 2 staged heads

  // coeff stage: whole 256-t tile, 2 heads
  {
    int h2 = tid >> 8, t = tid & 255;
    Cl[h2 * 256 + t] = cfw[((size_t)(b * 32 + (n0 >> 6) + h2)) * 2048 + t0 + t];
  }

  float accS = 0.f;
  float silLast = 0.f;
  f32x4 aa[5];

  // prologue: stage quarter 0 (80 rows, clamped for t<0)
  #pragma unroll
  for (int i = 0; i < 2; ++i){
    int idx = i * 512 + tid;
    if (idx < 640){
      int row = idx >> 3, c16 = idx & 7;
      int gt = t0 - 16 + row;
      if (gt < 0) gt = 0;
      int scol = (c16 * 8) ^ ((row & 7) << 3);
      gload16(xb + ((size_t)b * 2048 + gt) * 64 + scol, &Al[idx * 8]);
    }
  }

  for (int q = 0; q < 4; ++q){
    asm volatile("s_waitcnt vmcnt(0)" ::: "memory");
    __syncthreads();                       // Al(q) ready
    if (q == 0){
      // 5 row-tiles from the 80-row staged buffer (row j = t0-16+j)
      #pragma unroll
      for (int rt = 0; rt < 5; ++rt){
        f32x4 acc = {0.f, 0.f, 0.f, 0.f};
        int arow = rt * 16 + l15;
        int ae0 = (l4 * 8) ^ ((arow & 7) << 3);
        int ae1 = (32 + l4 * 8) ^ ((arow & 7) << 3);
        short8 af0 = *(const short8*)&Al[arow * 64 + ae0];
        short8 af1 = *(const short8*)&Al[arow * 64 + ae1];
        acc = __builtin_amdgcn_mfma_f32_16x16x32_bf16(af0, bf0, acc, 0, 0, 0);
        acc = __builtin_amdgcn_mfma_f32_16x16x32_bf16(af1, bf1, acc, 0, 0, 0);
        #pragma unroll
        for (int r = 0; r < 4; ++r) aa[rt][r] = acc[r] + bcw;
      }
    } else {
      // aa[0] carries history; 4 new tiles from 64-row staged buffer (row j = tq+j)
      #pragma unroll
      for (int rt = 1; rt < 5; ++rt){
        f32x4 acc = {0.f, 0.f, 0.f, 0.f};
        int arow = (rt - 1) * 16 + l15;
        int ae0 = (l4 * 8) ^ ((arow & 7) << 3);
        int ae1 = (32 + l4 * 8) ^ ((arow & 7) << 3);
        short8 af0 = *(const short8*)&Al[arow * 64 + ae0];
        short8 af1 = *(const short8*)&Al[arow * 64 + ae1];
        acc = __builtin_amdgcn_mfma_f32_16x16x32_bf16(af0, bf0, acc, 0, 0, 0);
        acc = __builtin_amdgcn_mfma_f32_16x16x32_bf16(af1, bf1, acc, 0, 0, 0);
        #pragma unroll
        for (int r = 0; r < 4; ++r) aa[rt][r] = acc[r] + bcw;
      }
    }
    __syncthreads();                       // Al dead
    // async-stage quarter q+1 (64 rows, 1 load/thread; overlaps conv below)
    if (q < 3){
      const int tq = t0 + (q + 1) * 64;
      int row = tid >> 3, c16 = tid & 7;
      int scol = (c16 * 8) ^ ((row & 7) << 3);
      gload16(xb + ((size_t)b * 2048 + tq + row) * 64 + scol, &Al[tid * 8]);
    }
    // register conv: rows rt*16 + l4*4 + r, taps from prev 4-row group
    #pragma unroll
    for (int rt = 1; rt < 5; ++rt){
      float P1, P2, P3;
      {
        float u1 = __shfl_up(aa[rt][1], 16, 64);
        float u2 = __shfl_up(aa[rt][2], 16, 64);
        float u3 = __shfl_up(aa[rt][3], 16, 64);
        float v1 = __shfl(aa[rt - 1][1], l15 + 48, 64);
        float v2 = __shfl(aa[rt - 1][2], l15 + 48, 64);
        float v3 = __shfl(aa[rt - 1][3], l15 + 48, 64);
        bool lo = (l4 == 0);
        P1 = lo ? v1 : u1;
        P2 = lo ? v2 : u2;
        P3 = lo ? v3 : u3;
        if (t0 == 0 && q == 0 && rt == 1 && lo){ P1 = 0.f; P2 = 0.f; P3 = 0.f; }
      }
      float x0 = aa[rt][0], x1 = aa[rt][1], x2 = aa[rt][2], x3 = aa[rt][3];
      float o0 = cbw + wcv[0] * P1 + wcv[1] * P2 + wcv[2] * P3 + wcv[3] * x0;
      float o1 = cbw + wcv[0] * P2 + wcv[1] * P3 + wcv[2] * x0 + wcv[3] * x1;
      float o2 = cbw + wcv[0] * P3 + wcv[1] * x0 + wcv[2] * x1 + wcv[3] * x2;
      float o3 = cbw + wcv[0] * x0 + wcv[1] * x1 + wcv[2] * x2 + wcv[3] * x3;
      float s0 = o0 / (1.f + __expf(-o0));
      float s1 = o1 / (1.f + __expf(-o1));
      float s2 = o2 / (1.f + __expf(-o2));
      float s3 = o3 / (1.f + __expf(-o3));
      const int tb = q * 64 + (rt - 1) * 16 + l4 * 4;
      const float* cfp = &Cl[hsel * 256 + tb];
      accS += cfp[0] * s0 + cfp[1] * s1 + cfp[2] * s2 + cfp[3] * s3;
      if (q == 3 && rt == 4) silLast = s3;
    }
    // carry history tile
    #pragma unroll
    for (int r = 0; r < 4; ++r) aa[0][r] = aa[4][r];
  }
  // xhlast (t = 2047): last m-tile, group l4==3 (rows ..2047)
  if ((mt & 7) == 7 && l4 == 3)
    xhl[b * 2048 + n0 + colw] = f2bf(silLast);
  // reduce across the 4 l4 groups (same channel), then one atomic per channel
  accS += __shfl_xor(accS, 16, 64);
  accS += __shfl_xor(accS, 32, 64);
  if (l4 == 0)
    atomicAdd(&yfin[b * 2048 + n0 + colw], accS);
}

// ---------------- gated RMSNorm (+D-term) ----------------
__global__ void k_norm(const float* __restrict__ yfin, const ushort_t* __restrict__ xhl,
                       const float* __restrict__ Dp, const float* __restrict__ z_last,
                       const float* __restrict__ norm_w, float* __restrict__ yn){
  __shared__ float red[256];
  int b = blockIdx.x, tid = threadIdx.x;
  float vals[8], ss = 0.f;
  #pragma unroll
  for (int j = 0; j < 8; ++j){
    int c = tid + 256 * j;
    float v = yfin[b * 2048 + c] + Dp[c >> 6] * bf2f(xhl[b * 2048 + c]);
    float z = z_last[b * 2048 + c];
    float yg = v * (z / (1.f + __expf(-z)));
    vals[j] = yg; ss += yg * yg;
  }
  red[tid] = ss; __syncthreads();
  for (int s = 128; s; s >>= 1){
    if (tid < s) red[tid] += red[tid + s];
    __syncthreads();
  }
  float scale = rsqrtf(red[0] / 2048.f + EPSV);
  #pragma unroll
  for (int j = 0; j < 8; ++j){
    int c = tid + 256 * j;
    yn[b * 2048 + c] = vals[j] * scale * norm_w[c];
  }
}

// ---------------- out projection: wave per column ----------------
__global__ __launch_bounds__(64)
void k_outproj(const float* __restrict__ yn, const float* __restrict__ wot,
               float* __restrict__ o){
  int col = blockIdx.x;
  int l = threadIdx.x;
  float acc[8] = {0.f, 0.f, 0.f, 0.f, 0.f, 0.f, 0.f, 0.f};
  const float* wp = wot + (size_t)col * 2048;
  #pragma unroll 4
  for (int i = 0; i < 32; ++i){
    int k = i * 64 + l;
    float w = wp[k];
    #pragma unroll
    for (int b = 0; b < 8; ++b)
      acc[b] += yn[b * 2048 + k] * w;
  }
  #pragma unroll
  for (int b = 0; b < 8; ++b){
    float v = acc[b];
    for (int s = 32; s; s >>= 1) v += __shfl_down(v, s, 64);
    if (l == 0) o[b * 1024 + col] = v;
  }
}

// ---------------- head: wave per output column ----------------
__global__ __launch_bounds__(64)
void k_head(const float* __restrict__ o, const float* __restrict__ wht,
            const float* __restrict__ b_head, float* __restrict__ out){
  int j = blockIdx.x;
  int l = threadIdx.x;
  float acc[8] = {0.f, 0.f, 0.f, 0.f, 0.f, 0.f, 0.f, 0.f};
  const float* wp = wht + (size_t)j * 1024;
  #pragma unroll 4
  for (int i = 0; i < 16; ++i){
    int k = i * 64 + l;
    float w = wp[k];
    #pragma unroll
    for (int b = 0; b < 8; ++b)
      acc[b] += o[b * 1024 + k] * w;
  }
  #pragma unroll
  for (int b = 0; b < 8; ++b){
    float v = acc[b];
    for (int s = 32; s; s >>= 1) v += __shfl_down(v, s, 64);
    if (l == 0) out[b * 64 + j] = v + b_head[j];
  }
}

extern "C" void kernel_launch(void* const* d_in, const int* in_sizes, int n_in,
                              void* d_out, int out_size, void* d_ws, size_t ws_size,
                              hipStream_t stream){
  (void)in_sizes; (void)n_in; (void)out_size; (void)ws_size;
  const float* x       = (const float*)d_in[0];
  const float* w_proj  = (const float*)d_in[1];
  const float* b_proj  = (const float*)d_in[2];
  const float* w_in    = (const float*)d_in[3];
  const float* conv_w  = (const float*)d_in[4];
  const float* conv_b  = (const float*)d_in[5];
  const float* A_log   = (const float*)d_in[6];
  const float* dt_bias = (const float*)d_in[7];
  const float* Dp      = (const float*)d_in[8];
  const float* norm_w  = (const float*)d_in[9];
  const float* w_out   = (const float*)d_in[10];
  const float* w_head  = (const float*)d_in[11];
  const float* b_head  = (const float*)d_in[12];
  float* out = (float*)d_out;

  char* ws = (char*)d_ws;
  size_t off = 0;
  auto alloc = [&](size_t bytes)->char*{
    char* p = ws + off; off += (bytes + 255) & ~(size_t)255; return p;
  };
  ushort_t* xb    = (ushort_t*)alloc((size_t)M_ROWS * 64 * 2);
  float*    wzT   = (float*)alloc((size_t)2048 * 1024 * 4);
  float*    wot   = (float*)alloc((size_t)1024 * 2048 * 4);
  float*    wht   = (float*)alloc((size_t)64 * 1024 * 4);
  float*    wpT   = (float*)alloc((size_t)1024 * 64 * 4);
  ushort_t* Afold = (ushort_t*)alloc((size_t)128 * 1024 * 2);
  ushort_t* w2tp  = (ushort_t*)alloc((size_t)2432 * 1024 * 2);
  ushort_t* Wcb   = (ushort_t*)alloc((size_t)2432 * 64 * 2);
  float*    bcv   = (float*)alloc((size_t)2432 * 4);
  float*    WdtT  = (float*)alloc((size_t)32 * 64 * 4);
  float*    bcdt  = (float*)alloc((size_t)32 * 4);
  float*    ul    = (float*)alloc((size_t)8 * 1024 * 4);
  ushort_t* xbcBC = (ushort_t*)alloc((size_t)M_ROWS * 256 * 2);
  float*    dtr   = (float*)alloc((size_t)M_ROWS * 32 * 4);
  float*    g     = (float*)alloc((size_t)M_ROWS * 4);
  float*    cfw   = (float*)alloc((size_t)256 * 2048 * 4);
  ushort_t* xhl   = (ushort_t*)alloc((size_t)8 * 2048 * 2);
  float*    yfin  = (float*)alloc((size_t)8 * 2048 * 4);
  float*    zl    = (float*)alloc((size_t)8 * 2048 * 4);
  float*    yn    = (float*)alloc((size_t)8 * 2048 * 4);
  float*    ov    = (float*)alloc((size_t)8 * 1024 * 4);

  k_prep<<<4096 + 512 + 512 + 16 + 16 + 512 + 608 + 64, 256, 0, stream>>>(
      x, w_proj, b_proj, w_in, w_out, w_head, xb, wzT, wot, wht, wpT, Afold, w2tp, yfin);

  k_foldg<<<19 + 32 + 32, 256, 0, stream>>>(Afold, w2tp, Wcb, bcv, xb, w_proj, b_proj, ul,
                                            wpT, w_in, WdtT, bcdt);

  k_gemmBC<<<BC_NB + DTR_NB + ZL_NB, 512, 0, stream>>>(
      xb, Wcb, bcv, xbcBC, WdtT, bcdt, dtr, ul, wzT, zl);

  dim3 gbc(64, 8);
  k_bcg2<<<gbc, 256, 0, stream>>>(xbcBC, conv_w, conv_b, g);

  k_coeff<<<256, 256, 0, stream>>>(dtr, dt_bias, A_log, g, cfw);

  dim3 gx(16, 64);
  k_xsum<<<gx, 512, 0, stream>>>(xb, Wcb, bcv, conv_w, conv_b, cfw, yfin, xhl);

  k_norm<<<8, 256, 0, stream>>>(yfin, xhl, Dp, zl, norm_w, yn);
  k_outproj<<<1024, 64, 0, stream>>>(yn, wot, ov);
  k_head<<<64, 64, 0, stream>>>(ov, wht, b_head, out);
}

// Round 24
// 133.843 us; speedup vs baseline: 1.0821x; 1.0821x over previous
//
#include <hip/hip_runtime.h>
#include <hip/hip_bf16.h>
#include <stdint.h>

typedef unsigned short ushort_t;
typedef __attribute__((ext_vector_type(8))) short short8;
typedef __attribute__((ext_vector_type(4))) short short4v;
typedef __attribute__((ext_vector_type(4))) unsigned short ushort4v;
typedef __attribute__((ext_vector_type(4))) float f32x4;

#define L_SEQ   2048
#define BATCH   8
#define M_ROWS  16384          // BATCH*L_SEQ
#define EPSV    1e-5f
#define BC_NB   128            // 64 m-tiles(256) x 2 n-tiles(128)
#define DTR_NB  1024           // 16 rows per block
#define ZL_NB   256            // 8 cols per block

__device__ __forceinline__ float bf2f(ushort_t u){
  union { uint32_t i; float f; } v; v.i = ((uint32_t)u) << 16; return v.f;
}
__device__ __forceinline__ ushort_t f2bf(float f){
  union { float f; uint32_t i; } v; v.f = f;
  uint32_t r = v.i + 0x7fffu + ((v.i >> 16) & 1u);
  return (ushort_t)(r >> 16);
}

// ---------------- prep: xb, fp32 transposes, Afold bf16, w2tp bf16, yfin zero ----------------
__global__ __launch_bounds__(256)
void k_prep(const float* __restrict__ x, const float* __restrict__ w_proj,
            const float* __restrict__ b_proj, const float* __restrict__ w_in,
            const float* __restrict__ w_out, const float* __restrict__ w_head,
            ushort_t* __restrict__ xb, float* __restrict__ wzT,
            float* __restrict__ wot, float* __restrict__ wht,
            float* __restrict__ wpT, ushort_t* __restrict__ Afold,
            ushort_t* __restrict__ w2tp, float* __restrict__ yfin){
  __shared__ float tile[64][65];
  int bx = blockIdx.x, tid = threadIdx.x;
  if (bx < 4096){                          // x -> bf16
    int i = bx * 256 + tid;
    xb[i] = f2bf(x[i]);
    return;
  }
  bx -= 4096;
  if (bx < 512 + 512 + 16 + 16){
    const float* src; float* dstf;
    int R, C, colOff, j0, k0; bool isWpT = false;
    if (bx < 512){               src = w_in;   dstf = wzT; R = 1024; C = 4384; colOff = 0; j0 = (bx % 32) * 64; k0 = (bx / 32) * 64; }
    else if ((bx -= 512) < 512){ src = w_out;  dstf = wot; R = 2048; C = 1024; colOff = 0; j0 = (bx % 16) * 64; k0 = (bx / 16) * 64; }
    else if ((bx -= 512) < 16){  src = w_head; dstf = wht; R = 1024; C = 64;   colOff = 0; j0 = 0;             k0 = bx * 64; }
    else { bx -= 16;             src = w_proj; dstf = wpT; R = 64;   C = 1024; colOff = 0; j0 = bx * 64;       k0 = 0; isWpT = true; }
    int tx = tid & 63, ty = tid >> 6;
    #pragma unroll
    for (int i = 0; i < 16; ++i){
      int kk = ty * 16 + i;
      if (!isWpT || (k0 + kk) < 64)
        tile[kk][tx] = src[(size_t)(k0 + kk) * C + colOff + j0 + tx];
    }
    __syncthreads();
    #pragma unroll
    for (int i = 0; i < 16; ++i){
      int jj = ty * 16 + i;
      if (isWpT) dstf[(size_t)(j0 + jj) * 64 + tx] = tile[tx][jj];
      else       dstf[(size_t)(j0 + jj) * R + k0 + tx] = tile[tx][jj];
    }
    return;
  }
  bx -= 1056;
  if (bx < 512){                           // Afold[128][1024] bf16
    int i = bx * 256 + tid;
    int row = i >> 10, col = i & 1023;
    float v = (row < 64) ? w_proj[(size_t)row * 1024 + col]
            : (row == 64) ? b_proj[col] : 0.f;
    Afold[i] = f2bf(v);
    return;
  }
  bx -= 512;
  if (bx < 608){                           // w2tp[2432][1024] bf16
    int j0 = (bx % 38) * 64;
    int k0 = (bx / 38) * 64;
    int tx = tid & 63, ty = tid >> 6;
    #pragma unroll
    for (int i = 0; i < 16; ++i){
      int kk = ty * 16 + i;
      int j = j0 + tx;
      tile[kk][tx] = (j < 2304) ? w_in[(size_t)(k0 + kk) * 4384 + 2048 + j] : 0.f;
    }
    __syncthreads();
    #pragma unroll
    for (int i = 0; i < 16; ++i){
      int jj = ty * 16 + i;
      w2tp[(size_t)(j0 + jj) * 1024 + k0 + tx] = f2bf(tile[tx][jj]);
    }
    return;
  }
  bx -= 608;
  yfin[bx * 256 + tid] = 0.f;              // 64 blocks: zero yfin (16384 floats)
}

// ---------------- async global->LDS ----------------
__device__ __forceinline__ void gload16(const void* g, void* l){
  __builtin_amdgcn_global_load_lds((const __attribute__((address_space(1))) void*)g,
                                   (__attribute__((address_space(3))) void*)l, 16, 0, 0);
}

// ---------------- MFMA fold GEMM (19) + u_last (32) + dt fold (32) ----------------
__global__ __launch_bounds__(256)
void k_foldg(const ushort_t* __restrict__ Afold, const ushort_t* __restrict__ w2tp,
             ushort_t* __restrict__ Wcb, float* __restrict__ bc,
             const ushort_t* __restrict__ xb, const float* __restrict__ w_proj,
             const float* __restrict__ b_proj, float* __restrict__ ul,
             const float* __restrict__ wpT, const float* __restrict__ w_in,
             float* __restrict__ WdtT, float* __restrict__ bcdt){
  __shared__ ushort_t tA[128 * 32];
  __shared__ ushort_t tB[128 * 32];
  __shared__ float redf[4][64];
  const int bid = blockIdx.x;
  const int tid = threadIdx.x;
  const int lane = tid & 63;
  const int wave = tid >> 6;

  if (bid >= 51){
    int h = bid - 51;
    int a = tid & 63, q = tid >> 6;
    const float* wcol = w_in + 4352 + h;
    float acc = 0.f;
    const int d0 = q * 256;
    for (int d = d0; d < d0 + 256; ++d)
      acc += wpT[(size_t)d * 64 + a] * wcol[(size_t)d * 4384];
    redf[q][a] = acc;
    __syncthreads();
    if (q == 0){
      WdtT[h * 64 + a] = redf[0][a] + redf[1][a] + redf[2][a] + redf[3][a];
      float bacc = 0.f;
      #pragma unroll 4
      for (int i = 0; i < 16; ++i){
        int d = a + 64 * i;
        bacc += b_proj[d] * wcol[(size_t)d * 4384];
      }
      for (int s = 32; s; s >>= 1) bacc += __shfl_down(bacc, s, 64);
      if (a == 0) bcdt[h] = bacc;
    }
    return;
  }

  if (bid >= 19){
    int i = (bid - 19) * 256 + tid;
    int b = i >> 10, d = i & 1023;
    float acc = b_proj[d];
    const ushort_t* xrow = xb + ((size_t)(b * 2048 + 2047)) * 64;
    #pragma unroll 8
    for (int k = 0; k < 64; ++k)
      acc += bf2f(xrow[k]) * w_proj[(size_t)k * 1024 + d];
    ul[b * 1024 + d] = acc;
    return;
  }

  const int n0 = bid * 128;
  const int wr = wave >> 1, wc = wave & 1;
  const int l15 = lane & 15, l4 = lane >> 4;
  const int srow  = lane >> 2;
  const int skoff = (lane & 3) * 8;

  f32x4 acc[4][4];
  #pragma unroll
  for (int m = 0; m < 4; ++m)
    #pragma unroll
    for (int n = 0; n < 4; ++n)
      #pragma unroll
      for (int r = 0; r < 4; ++r) acc[m][n][r] = 0.f;

  for (int k0 = 0; k0 < 1024; k0 += 32){
    #pragma unroll
    for (int r = 0; r < 2; ++r){
      int chunk = r * 4 + wave;
      int rr = chunk * 16 + srow;
      gload16(Afold + (size_t)rr * 1024 + k0 + skoff, &tA[chunk * 512]);
      gload16(w2tp  + (size_t)(n0 + rr) * 1024 + k0 + skoff, &tB[chunk * 512]);
    }
    __syncthreads();
    short8 af[4], bfv[4];
    #pragma unroll
    for (int m = 0; m < 4; ++m)
      af[m] = *(const short8*)&tA[(wr * 64 + m * 16 + l15) * 32 + l4 * 8];
    #pragma unroll
    for (int n = 0; n < 4; ++n)
      bfv[n] = *(const short8*)&tB[(wc * 64 + n * 16 + l15) * 32 + l4 * 8];
    #pragma unroll
    for (int m = 0; m < 4; ++m)
      #pragma unroll
      for (int n = 0; n < 4; ++n)
        acc[m][n] = __builtin_amdgcn_mfma_f32_16x16x32_bf16(af[m], bfv[n], acc[m][n], 0, 0, 0);
    __syncthreads();
  }
  #pragma unroll
  for (int n = 0; n < 4; ++n){
    int col = n0 + wc * 64 + n * 16 + l15;
    #pragma unroll
    for (int m = 0; m < 4; ++m){
      int rowb = wr * 64 + m * 16 + l4 * 4;
      #pragma unroll
      for (int r = 0; r < 4; ++r){
        int row = rowb + r;
        if (row < 64)       Wcb[(size_t)col * 64 + row] = f2bf(acc[m][n][r]);
        else if (row == 64) bc[col] = acc[m][n][r];
      }
    }
  }
}

// ---------------- BC cols GEMM (256x128 tiles) + dt_raw + z_last ----------------
__global__ __launch_bounds__(512)
void k_gemmBC(const ushort_t* __restrict__ A, const ushort_t* __restrict__ Wcb,
              const float* __restrict__ bc, ushort_t* __restrict__ CBC,
              const float* __restrict__ WdtT, const float* __restrict__ bcdt,
              float* __restrict__ dtr, const float* __restrict__ ul,
              const float* __restrict__ wzT, float* __restrict__ z_last){
  __shared__ ushort_t lds[24576];
  const int bid = blockIdx.x;
  const int tid = threadIdx.x;
  const int lane = tid & 63;
  const int wave = tid >> 6;

  if (bid >= BC_NB + DTR_NB){
    int col = (bid - BC_NB - DTR_NB) * 8 + wave;
    float acc[8] = {0.f, 0.f, 0.f, 0.f, 0.f, 0.f, 0.f, 0.f};
    const float* wp = wzT + (size_t)col * 1024;
    #pragma unroll 4
    for (int i = 0; i < 16; ++i){
      int k = i * 64 + lane;
      float w = wp[k];
      #pragma unroll
      for (int b = 0; b < 8; ++b)
        acc[b] += ul[b * 1024 + k] * w;
    }
    #pragma unroll
    for (int b = 0; b < 8; ++b){
      float v = acc[b];
      for (int s = 32; s; s >>= 1) v += __shfl_down(v, s, 64);
      if (lane == 0) z_last[b * 2048 + col] = v;
    }
    return;
  }

  if (bid >= BC_NB){
    int r = tid >> 5, h = tid & 31;
    size_t m = (size_t)(bid - BC_NB) * 16 + r;
    const ushort_t* xrow = A + m * 64;
    const float* wrow = WdtT + h * 64;
    float acc = bcdt[h];
    #pragma unroll 8
    for (int k = 0; k < 64; ++k)
      acc += bf2f(xrow[k]) * wrow[k];
    dtr[m * 32 + h] = acc;
    return;
  }

  const int cpx = BC_NB >> 3;
  const int swz = (bid & 7) * cpx + (bid >> 3);
  const int m0 = (swz >> 1) * 256, n0 = (swz & 1) * 128;
  const int l15 = lane & 15, l4 = lane >> 4;

  #pragma unroll
  for (int i = 0; i < 4; ++i){
    int idx = i * 512 + tid;
    int row = idx >> 3, c16 = idx & 7;
    int scol = (c16 * 8) ^ ((row & 7) << 3);
    gload16(A + (size_t)(m0 + row) * 64 + scol, &lds[idx * 8]);
  }
  #pragma unroll
  for (int i = 0; i < 2; ++i){
    int idx = i * 512 + tid;
    int row = idx >> 3, c16 = idx & 7;
    int scol = (c16 * 8) ^ ((row & 7) << 3);
    gload16(Wcb + (size_t)(2048 + n0 + row) * 64 + scol, &lds[16384 + idx * 8]);
  }
  __syncthreads();

  f32x4 acc[2][8];
  #pragma unroll
  for (int m = 0; m < 2; ++m)
    #pragma unroll
    for (int n = 0; n < 8; ++n)
      #pragma unroll
      for (int r = 0; r < 4; ++r) acc[m][n][r] = 0.f;

  #pragma unroll
  for (int kk = 0; kk < 2; ++kk){
    short8 af[2], bfv[8];
    #pragma unroll
    for (int m = 0; m < 2; ++m){
      int row = wave * 32 + m * 16 + l15;
      int e = (kk * 32 + l4 * 8) ^ ((row & 7) << 3);
      af[m] = *(const short8*)&lds[row * 64 + e];
    }
    #pragma unroll
    for (int n = 0; n < 8; ++n){
      int row = n * 16 + l15;
      int e = (kk * 32 + l4 * 8) ^ ((row & 7) << 3);
      bfv[n] = *(const short8*)&lds[16384 + row * 64 + e];
    }
    #pragma unroll
    for (int m = 0; m < 2; ++m)
      #pragma unroll
      for (int n = 0; n < 8; ++n)
        acc[m][n] = __builtin_amdgcn_mfma_f32_16x16x32_bf16(af[m], bfv[n], acc[m][n], 0, 0, 0);
  }
  __syncthreads();

  #pragma unroll
  for (int half = 0; half < 2; ++half){
    if ((wave >> 2) == half){
      int wl = wave & 3;
      #pragma unroll
      for (int n = 0; n < 8; ++n){
        int col = n * 16 + l15;
        float bv = bc[2048 + n0 + col];
        #pragma unroll
        for (int m = 0; m < 2; ++m){
          #pragma unroll
          for (int r = 0; r < 4; ++r){
            int lr = wl * 32 + m * 16 + l4 * 4 + r;
            lds[lr * 128 + (col ^ ((lr & 7) << 3))] = f2bf(acc[m][n][r] + bv);
          }
        }
      }
    }
    __syncthreads();
    #pragma unroll
    for (int p = 0; p < 4; ++p){
      int gr = p * 32 + (tid >> 4);
      int cg = (tid & 15) * 8;
      short8 v = *(const short8*)&lds[gr * 128 + (cg ^ ((gr & 7) << 3))];
      *(short8*)&CBC[(size_t)(m0 + half * 128 + gr) * 256 + n0 + cg] = v;
    }
    __syncthreads();
  }
}

// ---------------- fused conv(B,C)+SiLU+gdot: g[b,t] ----------------
__global__ __launch_bounds__(256)
void k_bcg2(const ushort_t* __restrict__ xbcBC, const float* __restrict__ conv_w,
            const float* __restrict__ conv_b, float* __restrict__ g){
  __shared__ float csh[128];
  __shared__ float wsh[128][4];
  __shared__ float bsh[128];
  const int b = blockIdx.y;
  const int t0 = blockIdx.x * 32;
  const int tid = threadIdx.x;
  const size_t rowb = (size_t)b * 2048;

  if (tid < 128){
    int cB = 2048 + tid;
    f32x4 wb = *(const f32x4*)&conv_w[cB * 4];
    #pragma unroll
    for (int k = 0; k < 4; ++k) wsh[tid][k] = wb[k];
    bsh[tid] = conv_b[cB];
    int c = 2176 + tid;
    f32x4 w4 = *(const f32x4*)&conv_w[c * 4];
    float a = conv_b[c];
    #pragma unroll
    for (int k = 0; k < 4; ++k)
      a += bf2f(xbcBC[(rowb + 2044 + k) * 256 + 128 + tid]) * w4[k];
    csh[tid] = a / (1.f + __expf(-a));
  }
  __syncthreads();

  const int t = t0 + (tid >> 3);
  const int lg = tid & 7;
  const int cb0 = lg * 16;
  short8 v0[4], v1[4];
  #pragma unroll
  for (int k = 0; k < 4; ++k){
    int tt = t - 3 + k;
    if (tt >= 0){
      v0[k] = *(const short8*)&xbcBC[(rowb + tt) * 256 + cb0];
      v1[k] = *(const short8*)&xbcBC[(rowb + tt) * 256 + cb0 + 8];
    } else {
      short8 z = {0,0,0,0,0,0,0,0}; v0[k] = z; v1[k] = z;
    }
  }
  float gacc = 0.f;
  #pragma unroll
  for (int j = 0; j < 8; ++j){
    int c = cb0 + j;
    float a = bsh[c];
    #pragma unroll
    for (int k = 0; k < 4; ++k) a += bf2f((ushort_t)v0[k][j]) * wsh[c][k];
    gacc += (a / (1.f + __expf(-a))) * csh[c];
  }
  #pragma unroll
  for (int j = 0; j < 8; ++j){
    int c = cb0 + 8 + j;
    float a = bsh[c];
    #pragma unroll
    for (int k = 0; k < 4; ++k) a += bf2f((ushort_t)v1[k][j]) * wsh[c][k];
    gacc += (a / (1.f + __expf(-a))) * csh[c];
  }
  #pragma unroll
  for (int s = 4; s; s >>= 1) gacc += __shfl_down(gacc, s, 8);
  if (lg == 0) g[rowb + t] = gacc;
}

// ---------------- per-(b,h) suffix scan -> coeff ----------------
__global__ void k_coeff(const float* __restrict__ dt_raw, const float* __restrict__ dt_bias,
                        const float* __restrict__ A_log, const float* __restrict__ g,
                        float* __restrict__ coeffw){
  __shared__ float csum[256];
  int bh = blockIdx.x;
  int b = bh >> 5, h = bh & 31;
  float Ah = -__expf(A_log[h]);
  float bias = dt_bias[h];
  int tid = threadIdx.x;
  size_t base = (size_t)b * 2048;
  float d[8], dts[8];
  #pragma unroll
  for (int j = 0; j < 8; ++j){
    int t = tid * 8 + j;
    float x = dt_raw[(base + t) * 32 + h] + bias;
    float sp = (x > 20.f) ? x : log1pf(__expf(x));
    dts[j] = sp;
    d[j] = sp * Ah;
  }
  float cs = 0.f;
  #pragma unroll
  for (int j = 0; j < 8; ++j) cs += d[j];
  csum[tid] = cs;
  __syncthreads();
  float suf = 0.f;
  for (int j = tid + 1; j < 256; ++j) suf += csum[j];
  float S = suf, outv[8];
  for (int j = 7; j >= 0; --j){ outv[j] = S; S += d[j]; }
  #pragma unroll
  for (int j = 0; j < 8; ++j){
    int t = tid * 8 + j;
    coeffw[(size_t)bh * 2048 + t] = __expf(outv[j]) * dts[j] * g[base + t];
  }
}

// ---------------- FUSED x-part: MFMA -> register conv+SiLU+coeff-sum -> yfin ----------------
// grid (16 n-blocks of 128 ch, 64 m-tiles of 256 t); 512 threads; 4 quarters of 64 t.
// Conv computed in registers from MFMA output (no Ol round-trip); taps via shfl.
__global__ __launch_bounds__(512)
void k_xsum(const ushort_t* __restrict__ xb, const ushort_t* __restrict__ Wcb,
            const float* __restrict__ bcv, const float* __restrict__ conv_w,
            const float* __restrict__ conv_b, const float* __restrict__ cfw,
            float* __restrict__ yfin, ushort_t* __restrict__ xhl){
  __shared__ char S[12288];
  ushort_t* Al = (ushort_t*)S;              // [80][64]  (10240 B)
  float*    Cl = (float*)(S + 10240);       // [2][256]  (2048 B)
  const int tid = threadIdx.x, lane = tid & 63, wave = tid >> 6;
  const int n0 = blockIdx.x * 128;
  const int mt = blockIdx.y;
  const int b = mt >> 3, t0 = (mt & 7) * 256;
  const int l15 = lane & 15, l4 = lane >> 4;

  // B-fragment + per-channel conv params in regs
  const int colw = wave * 16 + l15;
  const short8 bf0 = *(const short8*)&Wcb[(size_t)(n0 + colw) * 64 + l4 * 8];
  const short8 bf1 = *(const short8*)&Wcb[(size_t)(n0 + colw) * 64 + 32 + l4 * 8];
  const float bcw = bcv[n0 + colw];
  const f32x4 wcv = *(const f32x4*)&conv_w[(n0 + colw) * 4];
  const float cbw = conv_b[n0 + colw];
  const int hsel = (colw >> 6);             // head select within the 2 staged heads

  // coeff stage: whole 256-t tile, 2 heads
  {
    int h2 = tid >> 8, t = tid & 255;
    Cl[h2 * 256 + t] = cfw[((size_t)(b * 32 + (n0 >> 6) + h2)) * 2048 + t0 + t];
  }

  float accS = 0.f;
  float silLast = 0.f;

  // prologue: stage quarter 0 (rows clamped for t<0)
  #pragma unroll
  for (int i = 0; i < 2; ++i){
    int idx = i * 512 + tid;
    if (idx < 640){
      int row = idx >> 3, c16 = idx & 7;
      int gt = t0 - 16 + row;
      if (gt < 0) gt = 0;
      int scol = (c16 * 8) ^ ((row & 7) << 3);
      gload16(xb + ((size_t)b * 2048 + gt) * 64 + scol, &Al[idx * 8]);
    }
  }

  for (int q = 0; q < 4; ++q){
    asm volatile("s_waitcnt vmcnt(0)" ::: "memory");
    __syncthreads();                       // Al(q) ready
    // MFMA all 5 row-tiles -> aa[rt] (+ xbc bias)
    f32x4 aa[5];
    #pragma unroll
    for (int rt = 0; rt < 5; ++rt){
      f32x4 acc = {0.f, 0.f, 0.f, 0.f};
      int arow = rt * 16 + l15;
      int ae0 = (l4 * 8) ^ ((arow & 7) << 3);
      int ae1 = (32 + l4 * 8) ^ ((arow & 7) << 3);
      short8 af0 = *(const short8*)&Al[arow * 64 + ae0];
      short8 af1 = *(const short8*)&Al[arow * 64 + ae1];
      acc = __builtin_amdgcn_mfma_f32_16x16x32_bf16(af0, bf0, acc, 0, 0, 0);
      acc = __builtin_amdgcn_mfma_f32_16x16x32_bf16(af1, bf1, acc, 0, 0, 0);
      #pragma unroll
      for (int r = 0; r < 4; ++r) aa[rt][r] = acc[r] + bcw;
    }
    __syncthreads();                       // Al dead
    // async-stage quarter q+1 (overlaps conv below)
    if (q < 3){
      const int tq = t0 + (q + 1) * 64;
      #pragma unroll
      for (int i = 0; i < 2; ++i){
        int idx = i * 512 + tid;
        if (idx < 640){
          int row = idx >> 3, c16 = idx & 7;
          int gt = tq - 16 + row;
          int scol = (c16 * 8) ^ ((row & 7) << 3);
          gload16(xb + ((size_t)b * 2048 + gt) * 64 + scol, &Al[idx * 8]);
        }
      }
    }
    // register conv: rows rt*16 + l4*4 + r, taps from prev 4-row group
    #pragma unroll
    for (int rt = 1; rt < 5; ++rt){
      float P1, P2, P3;
      {
        float u1 = __shfl_up(aa[rt][1], 16, 64);
        float u2 = __shfl_up(aa[rt][2], 16, 64);
        float u3 = __shfl_up(aa[rt][3], 16, 64);
        float v1 = __shfl(aa[rt - 1][1], l15 + 48, 64);
        float v2 = __shfl(aa[rt - 1][2], l15 + 48, 64);
        float v3 = __shfl(aa[rt - 1][3], l15 + 48, 64);
        bool lo = (l4 == 0);
        P1 = lo ? v1 : u1;
        P2 = lo ? v2 : u2;
        P3 = lo ? v3 : u3;
        if (t0 == 0 && q == 0 && rt == 1 && lo){ P1 = 0.f; P2 = 0.f; P3 = 0.f; }
      }
      float x0 = aa[rt][0], x1 = aa[rt][1], x2 = aa[rt][2], x3 = aa[rt][3];
      float o0 = cbw + wcv[0] * P1 + wcv[1] * P2 + wcv[2] * P3 + wcv[3] * x0;
      float o1 = cbw + wcv[0] * P2 + wcv[1] * P3 + wcv[2] * x0 + wcv[3] * x1;
      float o2 = cbw + wcv[0] * P3 + wcv[1] * x0 + wcv[2] * x1 + wcv[3] * x2;
      float o3 = cbw + wcv[0] * x0 + wcv[1] * x1 + wcv[2] * x2 + wcv[3] * x3;
      float s0 = o0 / (1.f + __expf(-o0));
      float s1 = o1 / (1.f + __expf(-o1));
      float s2 = o2 / (1.f + __expf(-o2));
      float s3 = o3 / (1.f + __expf(-o3));
      const int tb = q * 64 + (rt - 1) * 16 + l4 * 4;
      const float* cfp = &Cl[hsel * 256 + tb];
      accS += cfp[0] * s0 + cfp[1] * s1 + cfp[2] * s2 + cfp[3] * s3;
      if (q == 3 && rt == 4) silLast = s3;
    }
  }
  // xhlast (t = 2047): last m-tile, group l4==3 (rows ..2047)
  if ((mt & 7) == 7 && l4 == 3)
    xhl[b * 2048 + n0 + colw] = f2bf(silLast);
  // reduce across the 4 l4 groups (same channel), then one atomic per channel
  accS += __shfl_xor(accS, 16, 64);
  accS += __shfl_xor(accS, 32, 64);
  if (l4 == 0)
    atomicAdd(&yfin[b * 2048 + n0 + colw], accS);
}

// ---------------- gated RMSNorm (+D-term) ----------------
__global__ void k_norm(const float* __restrict__ yfin, const ushort_t* __restrict__ xhl,
                       const float* __restrict__ Dp, const float* __restrict__ z_last,
                       const float* __restrict__ norm_w, float* __restrict__ yn){
  __shared__ float red[256];
  int b = blockIdx.x, tid = threadIdx.x;
  float vals[8], ss = 0.f;
  #pragma unroll
  for (int j = 0; j < 8; ++j){
    int c = tid + 256 * j;
    float v = yfin[b * 2048 + c] + Dp[c >> 6] * bf2f(xhl[b * 2048 + c]);
    float z = z_last[b * 2048 + c];
    float yg = v * (z / (1.f + __expf(-z)));
    vals[j] = yg; ss += yg * yg;
  }
  red[tid] = ss; __syncthreads();
  for (int s = 128; s; s >>= 1){
    if (tid < s) red[tid] += red[tid + s];
    __syncthreads();
  }
  float scale = rsqrtf(red[0] / 2048.f + EPSV);
  #pragma unroll
  for (int j = 0; j < 8; ++j){
    int c = tid + 256 * j;
    yn[b * 2048 + c] = vals[j] * scale * norm_w[c];
  }
}

// ---------------- out projection: wave per column ----------------
__global__ __launch_bounds__(64)
void k_outproj(const float* __restrict__ yn, const float* __restrict__ wot,
               float* __restrict__ o){
  int col = blockIdx.x;
  int l = threadIdx.x;
  float acc[8] = {0.f, 0.f, 0.f, 0.f, 0.f, 0.f, 0.f, 0.f};
  const float* wp = wot + (size_t)col * 2048;
  #pragma unroll 4
  for (int i = 0; i < 32; ++i){
    int k = i * 64 + l;
    float w = wp[k];
    #pragma unroll
    for (int b = 0; b < 8; ++b)
      acc[b] += yn[b * 2048 + k] * w;
  }
  #pragma unroll
  for (int b = 0; b < 8; ++b){
    float v = acc[b];
    for (int s = 32; s; s >>= 1) v += __shfl_down(v, s, 64);
    if (l == 0) o[b * 1024 + col] = v;
  }
}

// ---------------- head: wave per output column ----------------
__global__ __launch_bounds__(64)
void k_head(const float* __restrict__ o, const float* __restrict__ wht,
            const float* __restrict__ b_head, float* __restrict__ out){
  int j = blockIdx.x;
  int l = threadIdx.x;
  float acc[8] = {0.f, 0.f, 0.f, 0.f, 0.f, 0.f, 0.f, 0.f};
  const float* wp = wht + (size_t)j * 1024;
  #pragma unroll 4
  for (int i = 0; i < 16; ++i){
    int k = i * 64 + l;
    float w = wp[k];
    #pragma unroll
    for (int b = 0; b < 8; ++b)
      acc[b] += o[b * 1024 + k] * w;
  }
  #pragma unroll
  for (int b = 0; b < 8; ++b){
    float v = acc[b];
    for (int s = 32; s; s >>= 1) v += __shfl_down(v, s, 64);
    if (l == 0) out[b * 64 + j] = v + b_head[j];
  }
}

extern "C" void kernel_launch(void* const* d_in, const int* in_sizes, int n_in,
                              void* d_out, int out_size, void* d_ws, size_t ws_size,
                              hipStream_t stream){
  (void)in_sizes; (void)n_in; (void)out_size; (void)ws_size;
  const float* x       = (const float*)d_in[0];
  const float* w_proj  = (const float*)d_in[1];
  const float* b_proj  = (const float*)d_in[2];
  const float* w_in    = (const float*)d_in[3];
  const float* conv_w  = (const float*)d_in[4];
  const float* conv_b  = (const float*)d_in[5];
  const float* A_log   = (const float*)d_in[6];
  const float* dt_bias = (const float*)d_in[7];
  const float* Dp      = (const float*)d_in[8];
  const float* norm_w  = (const float*)d_in[9];
  const float* w_out   = (const float*)d_in[10];
  const float* w_head  = (const float*)d_in[11];
  const float* b_head  = (const float*)d_in[12];
  float* out = (float*)d_out;

  char* ws = (char*)d_ws;
  size_t off = 0;
  auto alloc = [&](size_t bytes)->char*{
    char* p = ws + off; off += (bytes + 255) & ~(size_t)255; return p;
  };
  ushort_t* xb    = (ushort_t*)alloc((size_t)M_ROWS * 64 * 2);
  float*    wzT   = (float*)alloc((size_t)2048 * 1024 * 4);
  float*    wot   = (float*)alloc((size_t)1024 * 2048 * 4);
  float*    wht   = (float*)alloc((size_t)64 * 1024 * 4);
  float*    wpT   = (float*)alloc((size_t)1024 * 64 * 4);
  ushort_t* Afold = (ushort_t*)alloc((size_t)128 * 1024 * 2);
  ushort_t* w2tp  = (ushort_t*)alloc((size_t)2432 * 1024 * 2);
  ushort_t* Wcb   = (ushort_t*)alloc((size_t)2432 * 64 * 2);
  float*    bcv   = (float*)alloc((size_t)2432 * 4);
  float*    WdtT  = (float*)alloc((size_t)32 * 64 * 4);
  float*    bcdt  = (float*)alloc((size_t)32 * 4);
  float*    ul    = (float*)alloc((size_t)8 * 1024 * 4);
  ushort_t* xbcBC = (ushort_t*)alloc((size_t)M_ROWS * 256 * 2);
  float*    dtr   = (float*)alloc((size_t)M_ROWS * 32 * 4);
  float*    g     = (float*)alloc((size_t)M_ROWS * 4);
  float*    cfw   = (float*)alloc((size_t)256 * 2048 * 4);
  ushort_t* xhl   = (ushort_t*)alloc((size_t)8 * 2048 * 2);
  float*    yfin  = (float*)alloc((size_t)8 * 2048 * 4);
  float*    zl    = (float*)alloc((size_t)8 * 2048 * 4);
  float*    yn    = (float*)alloc((size_t)8 * 2048 * 4);
  float*    ov    = (float*)alloc((size_t)8 * 1024 * 4);

  k_prep<<<4096 + 512 + 512 + 16 + 16 + 512 + 608 + 64, 256, 0, stream>>>(
      x, w_proj, b_proj, w_in, w_out, w_head, xb, wzT, wot, wht, wpT, Afold, w2tp, yfin);

  k_foldg<<<19 + 32 + 32, 256, 0, stream>>>(Afold, w2tp, Wcb, bcv, xb, w_proj, b_proj, ul,
                                            wpT, w_in, WdtT, bcdt);

  k_gemmBC<<<BC_NB + DTR_NB + ZL_NB, 512, 0, stream>>>(
      xb, Wcb, bcv, xbcBC, WdtT, bcdt, dtr, ul, wzT, zl);

  dim3 gbc(64, 8);
  k_bcg2<<<gbc, 256, 0, stream>>>(xbcBC, conv_w, conv_b, g);

  k_coeff<<<256, 256, 0, stream>>>(dtr, dt_bias, A_log, g, cfw);

  dim3 gx(16, 64);
  k_xsum<<<gx, 512, 0, stream>>>(xb, Wcb, bcv, conv_w, conv_b, cfw, yfin, xhl);

  k_norm<<<8, 256, 0, stream>>>(yfin, xhl, Dp, zl, norm_w, yn);
  k_outproj<<<1024, 64, 0, stream>>>(yn, wot, ov);
  k_head<<<64, 64, 0, stream>>>(ov, wht, b_head, out);
}

// Round 25
// 126.486 us; speedup vs baseline: 1.1450x; 1.0582x over previous
//
#include <hip/hip_runtime.h>
#include <hip/hip_bf16.h>
#include <stdint.h>

typedef unsigned short ushort_t;
typedef __attribute__((ext_vector_type(8))) short short8;
typedef __attribute__((ext_vector_type(4))) short short4v;
typedef __attribute__((ext_vector_type(4))) unsigned short ushort4v;
typedef __attribute__((ext_vector_type(4))) float f32x4;

#define L_SEQ   2048
#define BATCH   8
#define M_ROWS  16384          // BATCH*L_SEQ
#define EPSV    1e-5f
#define BC_NB   128            // 64 m-tiles(256) x 2 n-tiles(128)
#define DTR_NB  1024           // 16 rows per block
#define ZL_NB   256            // 8 cols per block

__device__ __forceinline__ float bf2f(ushort_t u){
  union { uint32_t i; float f; } v; v.i = ((uint32_t)u) << 16; return v.f;
}
__device__ __forceinline__ ushort_t f2bf(float f){
  union { float f; uint32_t i; } v; v.f = f;
  uint32_t r = v.i + 0x7fffu + ((v.i >> 16) & 1u);
  return (ushort_t)(r >> 16);
}

// ---------------- prep: xb, fp32 transposes, Afold bf16, w2tp bf16, yfin zero ----------------
__global__ __launch_bounds__(256)
void k_prep(const float* __restrict__ x, const float* __restrict__ w_proj,
            const float* __restrict__ b_proj, const float* __restrict__ w_in,
            const float* __restrict__ w_out, const float* __restrict__ w_head,
            ushort_t* __restrict__ xb, float* __restrict__ wzT,
            float* __restrict__ wot, float* __restrict__ wht,
            float* __restrict__ wpT, ushort_t* __restrict__ Afold,
            ushort_t* __restrict__ w2tp, float* __restrict__ yfin){
  __shared__ float tile[64][65];
  int bx = blockIdx.x, tid = threadIdx.x;
  if (bx < 4096){                          // x -> bf16
    int i = bx * 256 + tid;
    xb[i] = f2bf(x[i]);
    return;
  }
  bx -= 4096;
  if (bx < 512 + 512 + 16 + 16){
    const float* src; float* dstf;
    int R, C, colOff, j0, k0; bool isWpT = false;
    if (bx < 512){               src = w_in;   dstf = wzT; R = 1024; C = 4384; colOff = 0; j0 = (bx % 32) * 64; k0 = (bx / 32) * 64; }
    else if ((bx -= 512) < 512){ src = w_out;  dstf = wot; R = 2048; C = 1024; colOff = 0; j0 = (bx % 16) * 64; k0 = (bx / 16) * 64; }
    else if ((bx -= 512) < 16){  src = w_head; dstf = wht; R = 1024; C = 64;   colOff = 0; j0 = 0;             k0 = bx * 64; }
    else { bx -= 16;             src = w_proj; dstf = wpT; R = 64;   C = 1024; colOff = 0; j0 = bx * 64;       k0 = 0; isWpT = true; }
    int tx = tid & 63, ty = tid >> 6;
    #pragma unroll
    for (int i = 0; i < 16; ++i){
      int kk = ty * 16 + i;
      if (!isWpT || (k0 + kk) < 64)
        tile[kk][tx] = src[(size_t)(k0 + kk) * C + colOff + j0 + tx];
    }
    __syncthreads();
    #pragma unroll
    for (int i = 0; i < 16; ++i){
      int jj = ty * 16 + i;
      if (isWpT) dstf[(size_t)(j0 + jj) * 64 + tx] = tile[tx][jj];
      else       dstf[(size_t)(j0 + jj) * R + k0 + tx] = tile[tx][jj];
    }
    return;
  }
  bx -= 1056;
  if (bx < 512){                           // Afold[128][1024] bf16
    int i = bx * 256 + tid;
    int row = i >> 10, col = i & 1023;
    float v = (row < 64) ? w_proj[(size_t)row * 1024 + col]
            : (row == 64) ? b_proj[col] : 0.f;
    Afold[i] = f2bf(v);
    return;
  }
  bx -= 512;
  if (bx < 608){                           // w2tp[2432][1024] bf16
    int j0 = (bx % 38) * 64;
    int k0 = (bx / 38) * 64;
    int tx = tid & 63, ty = tid >> 6;
    #pragma unroll
    for (int i = 0; i < 16; ++i){
      int kk = ty * 16 + i;
      int j = j0 + tx;
      tile[kk][tx] = (j < 2304) ? w_in[(size_t)(k0 + kk) * 4384 + 2048 + j] : 0.f;
    }
    __syncthreads();
    #pragma unroll
    for (int i = 0; i < 16; ++i){
      int jj = ty * 16 + i;
      w2tp[(size_t)(j0 + jj) * 1024 + k0 + tx] = f2bf(tile[tx][jj]);
    }
    return;
  }
  bx -= 608;
  yfin[bx * 256 + tid] = 0.f;              // 64 blocks: zero yfin (16384 floats)
}

// ---------------- async global->LDS ----------------
__device__ __forceinline__ void gload16(const void* g, void* l){
  __builtin_amdgcn_global_load_lds((const __attribute__((address_space(1))) void*)g,
                                   (__attribute__((address_space(3))) void*)l, 16, 0, 0);
}

// ---------------- MFMA fold GEMM (19) + u_last (32) + dt fold (32) ----------------
__global__ __launch_bounds__(256)
void k_foldg(const ushort_t* __restrict__ Afold, const ushort_t* __restrict__ w2tp,
             ushort_t* __restrict__ Wcb, float* __restrict__ bc,
             const ushort_t* __restrict__ xb, const float* __restrict__ w_proj,
             const float* __restrict__ b_proj, float* __restrict__ ul,
             const float* __restrict__ wpT, const float* __restrict__ w_in,
             float* __restrict__ WdtT, float* __restrict__ bcdt){
  __shared__ ushort_t tA[128 * 32];
  __shared__ ushort_t tB[128 * 32];
  __shared__ float redf[4][64];
  const int bid = blockIdx.x;
  const int tid = threadIdx.x;
  const int lane = tid & 63;
  const int wave = tid >> 6;

  if (bid >= 51){
    int h = bid - 51;
    int a = tid & 63, q = tid >> 6;
    const float* wcol = w_in + 4352 + h;
    float acc = 0.f;
    const int d0 = q * 256;
    for (int d = d0; d < d0 + 256; ++d)
      acc += wpT[(size_t)d * 64 + a] * wcol[(size_t)d * 4384];
    redf[q][a] = acc;
    __syncthreads();
    if (q == 0){
      WdtT[h * 64 + a] = redf[0][a] + redf[1][a] + redf[2][a] + redf[3][a];
      float bacc = 0.f;
      #pragma unroll 4
      for (int i = 0; i < 16; ++i){
        int d = a + 64 * i;
        bacc += b_proj[d] * wcol[(size_t)d * 4384];
      }
      for (int s = 32; s; s >>= 1) bacc += __shfl_down(bacc, s, 64);
      if (a == 0) bcdt[h] = bacc;
    }
    return;
  }

  if (bid >= 19){
    int i = (bid - 19) * 256 + tid;
    int b = i >> 10, d = i & 1023;
    float acc = b_proj[d];
    const ushort_t* xrow = xb + ((size_t)(b * 2048 + 2047)) * 64;
    #pragma unroll 8
    for (int k = 0; k < 64; ++k)
      acc += bf2f(xrow[k]) * w_proj[(size_t)k * 1024 + d];
    ul[b * 1024 + d] = acc;
    return;
  }

  const int n0 = bid * 128;
  const int wr = wave >> 1, wc = wave & 1;
  const int l15 = lane & 15, l4 = lane >> 4;
  const int srow  = lane >> 2;
  const int skoff = (lane & 3) * 8;

  f32x4 acc[4][4];
  #pragma unroll
  for (int m = 0; m < 4; ++m)
    #pragma unroll
    for (int n = 0; n < 4; ++n)
      #pragma unroll
      for (int r = 0; r < 4; ++r) acc[m][n][r] = 0.f;

  for (int k0 = 0; k0 < 1024; k0 += 32){
    #pragma unroll
    for (int r = 0; r < 2; ++r){
      int chunk = r * 4 + wave;
      int rr = chunk * 16 + srow;
      gload16(Afold + (size_t)rr * 1024 + k0 + skoff, &tA[chunk * 512]);
      gload16(w2tp  + (size_t)(n0 + rr) * 1024 + k0 + skoff, &tB[chunk * 512]);
    }
    __syncthreads();
    short8 af[4], bfv[4];
    #pragma unroll
    for (int m = 0; m < 4; ++m)
      af[m] = *(const short8*)&tA[(wr * 64 + m * 16 + l15) * 32 + l4 * 8];
    #pragma unroll
    for (int n = 0; n < 4; ++n)
      bfv[n] = *(const short8*)&tB[(wc * 64 + n * 16 + l15) * 32 + l4 * 8];
    #pragma unroll
    for (int m = 0; m < 4; ++m)
      #pragma unroll
      for (int n = 0; n < 4; ++n)
        acc[m][n] = __builtin_amdgcn_mfma_f32_16x16x32_bf16(af[m], bfv[n], acc[m][n], 0, 0, 0);
    __syncthreads();
  }
  #pragma unroll
  for (int n = 0; n < 4; ++n){
    int col = n0 + wc * 64 + n * 16 + l15;
    #pragma unroll
    for (int m = 0; m < 4; ++m){
      int rowb = wr * 64 + m * 16 + l4 * 4;
      #pragma unroll
      for (int r = 0; r < 4; ++r){
        int row = rowb + r;
        if (row < 64)       Wcb[(size_t)col * 64 + row] = f2bf(acc[m][n][r]);
        else if (row == 64) bc[col] = acc[m][n][r];
      }
    }
  }
}

// ---------------- BC cols GEMM (256x128 tiles) + dt_raw + z_last ----------------
__global__ __launch_bounds__(512)
void k_gemmBC(const ushort_t* __restrict__ A, const ushort_t* __restrict__ Wcb,
              const float* __restrict__ bc, ushort_t* __restrict__ CBC,
              const float* __restrict__ WdtT, const float* __restrict__ bcdt,
              float* __restrict__ dtr, const float* __restrict__ ul,
              const float* __restrict__ wzT, float* __restrict__ z_last){
  __shared__ ushort_t lds[24576];
  const int bid = blockIdx.x;
  const int tid = threadIdx.x;
  const int lane = tid & 63;
  const int wave = tid >> 6;

  if (bid >= BC_NB + DTR_NB){
    int col = (bid - BC_NB - DTR_NB) * 8 + wave;
    float acc[8] = {0.f, 0.f, 0.f, 0.f, 0.f, 0.f, 0.f, 0.f};
    const float* wp = wzT + (size_t)col * 1024;
    #pragma unroll 4
    for (int i = 0; i < 16; ++i){
      int k = i * 64 + lane;
      float w = wp[k];
      #pragma unroll
      for (int b = 0; b < 8; ++b)
        acc[b] += ul[b * 1024 + k] * w;
    }
    #pragma unroll
    for (int b = 0; b < 8; ++b){
      float v = acc[b];
      for (int s = 32; s; s >>= 1) v += __shfl_down(v, s, 64);
      if (lane == 0) z_last[b * 2048 + col] = v;
    }
    return;
  }

  if (bid >= BC_NB){
    int r = tid >> 5, h = tid & 31;
    size_t m = (size_t)(bid - BC_NB) * 16 + r;
    const ushort_t* xrow = A + m * 64;
    const float* wrow = WdtT + h * 64;
    float acc = bcdt[h];
    #pragma unroll 8
    for (int k = 0; k < 64; ++k)
      acc += bf2f(xrow[k]) * wrow[k];
    dtr[m * 32 + h] = acc;
    return;
  }

  const int cpx = BC_NB >> 3;
  const int swz = (bid & 7) * cpx + (bid >> 3);
  const int m0 = (swz >> 1) * 256, n0 = (swz & 1) * 128;
  const int l15 = lane & 15, l4 = lane >> 4;

  #pragma unroll
  for (int i = 0; i < 4; ++i){
    int idx = i * 512 + tid;
    int row = idx >> 3, c16 = idx & 7;
    int scol = (c16 * 8) ^ ((row & 7) << 3);
    gload16(A + (size_t)(m0 + row) * 64 + scol, &lds[idx * 8]);
  }
  #pragma unroll
  for (int i = 0; i < 2; ++i){
    int idx = i * 512 + tid;
    int row = idx >> 3, c16 = idx & 7;
    int scol = (c16 * 8) ^ ((row & 7) << 3);
    gload16(Wcb + (size_t)(2048 + n0 + row) * 64 + scol, &lds[16384 + idx * 8]);
  }
  __syncthreads();

  f32x4 acc[2][8];
  #pragma unroll
  for (int m = 0; m < 2; ++m)
    #pragma unroll
    for (int n = 0; n < 8; ++n)
      #pragma unroll
      for (int r = 0; r < 4; ++r) acc[m][n][r] = 0.f;

  #pragma unroll
  for (int kk = 0; kk < 2; ++kk){
    short8 af[2], bfv[8];
    #pragma unroll
    for (int m = 0; m < 2; ++m){
      int row = wave * 32 + m * 16 + l15;
      int e = (kk * 32 + l4 * 8) ^ ((row & 7) << 3);
      af[m] = *(const short8*)&lds[row * 64 + e];
    }
    #pragma unroll
    for (int n = 0; n < 8; ++n){
      int row = n * 16 + l15;
      int e = (kk * 32 + l4 * 8) ^ ((row & 7) << 3);
      bfv[n] = *(const short8*)&lds[16384 + row * 64 + e];
    }
    #pragma unroll
    for (int m = 0; m < 2; ++m)
      #pragma unroll
      for (int n = 0; n < 8; ++n)
        acc[m][n] = __builtin_amdgcn_mfma_f32_16x16x32_bf16(af[m], bfv[n], acc[m][n], 0, 0, 0);
  }
  __syncthreads();

  #pragma unroll
  for (int half = 0; half < 2; ++half){
    if ((wave >> 2) == half){
      int wl = wave & 3;
      #pragma unroll
      for (int n = 0; n < 8; ++n){
        int col = n * 16 + l15;
        float bv = bc[2048 + n0 + col];
        #pragma unroll
        for (int m = 0; m < 2; ++m){
          #pragma unroll
          for (int r = 0; r < 4; ++r){
            int lr = wl * 32 + m * 16 + l4 * 4 + r;
            lds[lr * 128 + (col ^ ((lr & 7) << 3))] = f2bf(acc[m][n][r] + bv);
          }
        }
      }
    }
    __syncthreads();
    #pragma unroll
    for (int p = 0; p < 4; ++p){
      int gr = p * 32 + (tid >> 4);
      int cg = (tid & 15) * 8;
      short8 v = *(const short8*)&lds[gr * 128 + (cg ^ ((gr & 7) << 3))];
      *(short8*)&CBC[(size_t)(m0 + half * 128 + gr) * 256 + n0 + cg] = v;
    }
    __syncthreads();
  }
}

// ---------------- fused conv(B,C)+SiLU+gdot: g[b,t] ----------------
__global__ __launch_bounds__(256)
void k_bcg2(const ushort_t* __restrict__ xbcBC, const float* __restrict__ conv_w,
            const float* __restrict__ conv_b, float* __restrict__ g){
  __shared__ float csh[128];
  __shared__ float wsh[128][4];
  __shared__ float bsh[128];
  const int b = blockIdx.y;
  const int t0 = blockIdx.x * 32;
  const int tid = threadIdx.x;
  const size_t rowb = (size_t)b * 2048;

  if (tid < 128){
    int cB = 2048 + tid;
    f32x4 wb = *(const f32x4*)&conv_w[cB * 4];
    #pragma unroll
    for (int k = 0; k < 4; ++k) wsh[tid][k] = wb[k];
    bsh[tid] = conv_b[cB];
    int c = 2176 + tid;
    f32x4 w4 = *(const f32x4*)&conv_w[c * 4];
    float a = conv_b[c];
    #pragma unroll
    for (int k = 0; k < 4; ++k)
      a += bf2f(xbcBC[(rowb + 2044 + k) * 256 + 128 + tid]) * w4[k];
    csh[tid] = a / (1.f + __expf(-a));
  }
  __syncthreads();

  const int t = t0 + (tid >> 3);
  const int lg = tid & 7;
  const int cb0 = lg * 16;
  short8 v0[4], v1[4];
  #pragma unroll
  for (int k = 0; k < 4; ++k){
    int tt = t - 3 + k;
    if (tt >= 0){
      v0[k] = *(const short8*)&xbcBC[(rowb + tt) * 256 + cb0];
      v1[k] = *(const short8*)&xbcBC[(rowb + tt) * 256 + cb0 + 8];
    } else {
      short8 z = {0,0,0,0,0,0,0,0}; v0[k] = z; v1[k] = z;
    }
  }
  float gacc = 0.f;
  #pragma unroll
  for (int j = 0; j < 8; ++j){
    int c = cb0 + j;
    float a = bsh[c];
    #pragma unroll
    for (int k = 0; k < 4; ++k) a += bf2f((ushort_t)v0[k][j]) * wsh[c][k];
    gacc += (a / (1.f + __expf(-a))) * csh[c];
  }
  #pragma unroll
  for (int j = 0; j < 8; ++j){
    int c = cb0 + 8 + j;
    float a = bsh[c];
    #pragma unroll
    for (int k = 0; k < 4; ++k) a += bf2f((ushort_t)v1[k][j]) * wsh[c][k];
    gacc += (a / (1.f + __expf(-a))) * csh[c];
  }
  #pragma unroll
  for (int s = 4; s; s >>= 1) gacc += __shfl_down(gacc, s, 8);
  if (lg == 0) g[rowb + t] = gacc;
}

// ---------------- per-(b,h) suffix scan -> coeff (Hillis-Steele scan) ----------------
__global__ void k_coeff(const float* __restrict__ dt_raw, const float* __restrict__ dt_bias,
                        const float* __restrict__ A_log, const float* __restrict__ g,
                        float* __restrict__ coeffw){
  __shared__ float csum[256];
  int bh = blockIdx.x;
  int b = bh >> 5, h = bh & 31;
  float Ah = -__expf(A_log[h]);
  float bias = dt_bias[h];
  int tid = threadIdx.x;
  size_t base = (size_t)b * 2048;
  float d[8], dts[8];
  #pragma unroll
  for (int j = 0; j < 8; ++j){
    int t = tid * 8 + j;
    float x = dt_raw[(base + t) * 32 + h] + bias;
    float sp = (x > 20.f) ? x : log1pf(__expf(x));
    dts[j] = sp;
    d[j] = sp * Ah;
  }
  float cs = 0.f;
  #pragma unroll
  for (int j = 0; j < 8; ++j) cs += d[j];
  // inclusive Hillis-Steele scan over the 256 chunk sums
  float incl = cs;
  csum[tid] = incl;
  __syncthreads();
  #pragma unroll
  for (int off = 1; off < 256; off <<= 1){
    float add = (tid >= off) ? csum[tid - off] : 0.f;
    __syncthreads();
    incl += add;
    csum[tid] = incl;
    __syncthreads();
  }
  float total = csum[255];
  float suf = total - incl;        // sum of chunks j > tid
  float S = suf, outv[8];
  for (int j = 7; j >= 0; --j){ outv[j] = S; S += d[j]; }
  #pragma unroll
  for (int j = 0; j < 8; ++j){
    int t = tid * 8 + j;
    coeffw[(size_t)bh * 2048 + t] = __expf(outv[j]) * dts[j] * g[base + t];
  }
}

// ---------------- FUSED x-part: MFMA -> register conv+SiLU+coeff-sum -> yfin ----------------
// grid (16 n-blocks of 128 ch, 64 m-tiles of 256 t); 512 threads; 4 quarters of 64 t.
// Conv computed in registers from MFMA output (no Ol round-trip); taps via shfl.
__global__ __launch_bounds__(512)
void k_xsum(const ushort_t* __restrict__ xb, const ushort_t* __restrict__ Wcb,
            const float* __restrict__ bcv, const float* __restrict__ conv_w,
            const float* __restrict__ conv_b, const float* __restrict__ cfw,
            float* __restrict__ yfin, ushort_t* __restrict__ xhl){
  __shared__ char S[12288];
  ushort_t* Al = (ushort_t*)S;              // [80][64]  (10240 B)
  float*    Cl = (float*)(S + 10240);       // [2][256]  (2048 B)
  const int tid = threadIdx.x, lane = tid & 63, wave = tid >> 6;
  const int n0 = blockIdx.x * 128;
  const int mt = blockIdx.y;
  const int b = mt >> 3, t0 = (mt & 7) * 256;
  const int l15 = lane & 15, l4 = lane >> 4;

  // B-fragment + per-channel conv params in regs
  const int colw = wave * 16 + l15;
  const short8 bf0 = *(const short8*)&Wcb[(size_t)(n0 + colw) * 64 + l4 * 8];
  const short8 bf1 = *(const short8*)&Wcb[(size_t)(n0 + colw) * 64 + 32 + l4 * 8];
  const float bcw = bcv[n0 + colw];
  const f32x4 wcv = *(const f32x4*)&conv_w[(n0 + colw) * 4];
  const float cbw = conv_b[n0 + colw];
  const int hsel = (colw >> 6);             // head select within the 2 staged heads

  // coeff stage: whole 256-t tile, 2 heads
  {
    int h2 = tid >> 8, t = tid & 255;
    Cl[h2 * 256 + t] = cfw[((size_t)(b * 32 + (n0 >> 6) + h2)) * 2048 + t0 + t];
  }

  float accS = 0.f;
  float silLast = 0.f;

  // prologue: stage quarter 0 (rows clamped for t<0)
  #pragma unroll
  for (int i = 0; i < 2; ++i){
    int idx = i * 512 + tid;
    if (idx < 640){
      int row = idx >> 3, c16 = idx & 7;
      int gt = t0 - 16 + row;
      if (gt < 0) gt = 0;
      int scol = (c16 * 8) ^ ((row & 7) << 3);
      gload16(xb + ((size_t)b * 2048 + gt) * 64 + scol, &Al[idx * 8]);
    }
  }

  for (int q = 0; q < 4; ++q){
    asm volatile("s_waitcnt vmcnt(0)" ::: "memory");
    __syncthreads();                       // Al(q) ready
    // MFMA all 5 row-tiles -> aa[rt] (+ xbc bias)
    f32x4 aa[5];
    #pragma unroll
    for (int rt = 0; rt < 5; ++rt){
      f32x4 acc = {0.f, 0.f, 0.f, 0.f};
      int arow = rt * 16 + l15;
      int ae0 = (l4 * 8) ^ ((arow & 7) << 3);
      int ae1 = (32 + l4 * 8) ^ ((arow & 7) << 3);
      short8 af0 = *(const short8*)&Al[arow * 64 + ae0];
      short8 af1 = *(const short8*)&Al[arow * 64 + ae1];
      acc = __builtin_amdgcn_mfma_f32_16x16x32_bf16(af0, bf0, acc, 0, 0, 0);
      acc = __builtin_amdgcn_mfma_f32_16x16x32_bf16(af1, bf1, acc, 0, 0, 0);
      #pragma unroll
      for (int r = 0; r < 4; ++r) aa[rt][r] = acc[r] + bcw;
    }
    __syncthreads();                       // Al dead
    // async-stage quarter q+1 (overlaps conv below)
    if (q < 3){
      const int tq = t0 + (q + 1) * 64;
      #pragma unroll
      for (int i = 0; i < 2; ++i){
        int idx = i * 512 + tid;
        if (idx < 640){
          int row = idx >> 3, c16 = idx & 7;
          int gt = tq - 16 + row;
          int scol = (c16 * 8) ^ ((row & 7) << 3);
          gload16(xb + ((size_t)b * 2048 + gt) * 64 + scol, &Al[idx * 8]);
        }
      }
    }
    // register conv: rows rt*16 + l4*4 + r, taps from prev 4-row group
    #pragma unroll
    for (int rt = 1; rt < 5; ++rt){
      float P1, P2, P3;
      {
        float u1 = __shfl_up(aa[rt][1], 16, 64);
        float u2 = __shfl_up(aa[rt][2], 16, 64);
        float u3 = __shfl_up(aa[rt][3], 16, 64);
        float v1 = __shfl(aa[rt - 1][1], l15 + 48, 64);
        float v2 = __shfl(aa[rt - 1][2], l15 + 48, 64);
        float v3 = __shfl(aa[rt - 1][3], l15 + 48, 64);
        bool lo = (l4 == 0);
        P1 = lo ? v1 : u1;
        P2 = lo ? v2 : u2;
        P3 = lo ? v3 : u3;
        if (t0 == 0 && q == 0 && rt == 1 && lo){ P1 = 0.f; P2 = 0.f; P3 = 0.f; }
      }
      float x0 = aa[rt][0], x1 = aa[rt][1], x2 = aa[rt][2], x3 = aa[rt][3];
      float o0 = cbw + wcv[0] * P1 + wcv[1] * P2 + wcv[2] * P3 + wcv[3] * x0;
      float o1 = cbw + wcv[0] * P2 + wcv[1] * P3 + wcv[2] * x0 + wcv[3] * x1;
      float o2 = cbw + wcv[0] * P3 + wcv[1] * x0 + wcv[2] * x1 + wcv[3] * x2;
      float o3 = cbw + wcv[0] * x0 + wcv[1] * x1 + wcv[2] * x2 + wcv[3] * x3;
      float s0 = o0 / (1.f + __expf(-o0));
      float s1 = o1 / (1.f + __expf(-o1));
      float s2 = o2 / (1.f + __expf(-o2));
      float s3 = o3 / (1.f + __expf(-o3));
      const int tb = q * 64 + (rt - 1) * 16 + l4 * 4;
      const float* cfp = &Cl[hsel * 256 + tb];
      accS += cfp[0] * s0 + cfp[1] * s1 + cfp[2] * s2 + cfp[3] * s3;
      if (q == 3 && rt == 4) silLast = s3;
    }
  }
  // xhlast (t = 2047): last m-tile, group l4==3 (rows ..2047)
  if ((mt & 7) == 7 && l4 == 3)
    xhl[b * 2048 + n0 + colw] = f2bf(silLast);
  // reduce across the 4 l4 groups (same channel), then one atomic per channel
  accS += __shfl_xor(accS, 16, 64);
  accS += __shfl_xor(accS, 32, 64);
  if (l4 == 0)
    atomicAdd(&yfin[b * 2048 + n0 + colw], accS);
}

// ---------------- gated RMSNorm (+D-term) ----------------
__global__ void k_norm(const float* __restrict__ yfin, const ushort_t* __restrict__ xhl,
                       const float* __restrict__ Dp, const float* __restrict__ z_last,
                       const float* __restrict__ norm_w, float* __restrict__ yn){
  __shared__ float red[256];
  int b = blockIdx.x, tid = threadIdx.x;
  float vals[8], ss = 0.f;
  #pragma unroll
  for (int j = 0; j < 8; ++j){
    int c = tid + 256 * j;
    float v = yfin[b * 2048 + c] + Dp[c >> 6] * bf2f(xhl[b * 2048 + c]);
    float z = z_last[b * 2048 + c];
    float yg = v * (z / (1.f + __expf(-z)));
    vals[j] = yg; ss += yg * yg;
  }
  red[tid] = ss; __syncthreads();
  for (int s = 128; s; s >>= 1){
    if (tid < s) red[tid] += red[tid + s];
    __syncthreads();
  }
  float scale = rsqrtf(red[0] / 2048.f + EPSV);
  #pragma unroll
  for (int j = 0; j < 8; ++j){
    int c = tid + 256 * j;
    yn[b * 2048 + c] = vals[j] * scale * norm_w[c];
  }
}

// ---------------- out projection: wave per column ----------------
__global__ __launch_bounds__(64)
void k_outproj(const float* __restrict__ yn, const float* __restrict__ wot,
               float* __restrict__ o){
  int col = blockIdx.x;
  int l = threadIdx.x;
  float acc[8] = {0.f, 0.f, 0.f, 0.f, 0.f, 0.f, 0.f, 0.f};
  const float* wp = wot + (size_t)col * 2048;
  #pragma unroll 4
  for (int i = 0; i < 32; ++i){
    int k = i * 64 + l;
    float w = wp[k];
    #pragma unroll
    for (int b = 0; b < 8; ++b)
      acc[b] += yn[b * 2048 + k] * w;
  }
  #pragma unroll
  for (int b = 0; b < 8; ++b){
    float v = acc[b];
    for (int s = 32; s; s >>= 1) v += __shfl_down(v, s, 64);
    if (l == 0) o[b * 1024 + col] = v;
  }
}

// ---------------- head: wave per output column ----------------
__global__ __launch_bounds__(64)
void k_head(const float* __restrict__ o, const float* __restrict__ wht,
            const float* __restrict__ b_head, float* __restrict__ out){
  int j = blockIdx.x;
  int l = threadIdx.x;
  float acc[8] = {0.f, 0.f, 0.f, 0.f, 0.f, 0.f, 0.f, 0.f};
  const float* wp = wht + (size_t)j * 1024;
  #pragma unroll 4
  for (int i = 0; i < 16; ++i){
    int k = i * 64 + l;
    float w = wp[k];
    #pragma unroll
    for (int b = 0; b < 8; ++b)
      acc[b] += o[b * 1024 + k] * w;
  }
  #pragma unroll
  for (int b = 0; b < 8; ++b){
    float v = acc[b];
    for (int s = 32; s; s >>= 1) v += __shfl_down(v, s, 64);
    if (l == 0) out[b * 64 + j] = v + b_head[j];
  }
}

extern "C" void kernel_launch(void* const* d_in, const int* in_sizes, int n_in,
                              void* d_out, int out_size, void* d_ws, size_t ws_size,
                              hipStream_t stream){
  (void)in_sizes; (void)n_in; (void)out_size; (void)ws_size;
  const float* x       = (const float*)d_in[0];
  const float* w_proj  = (const float*)d_in[1];
  const float* b_proj  = (const float*)d_in[2];
  const float* w_in    = (const float*)d_in[3];
  const float* conv_w  = (const float*)d_in[4];
  const float* conv_b  = (const float*)d_in[5];
  const float* A_log   = (const float*)d_in[6];
  const float* dt_bias = (const float*)d_in[7];
  const float* Dp      = (const float*)d_in[8];
  const float* norm_w  = (const float*)d_in[9];
  const float* w_out   = (const float*)d_in[10];
  const float* w_head  = (const float*)d_in[11];
  const float* b_head  = (const float*)d_in[12];
  float* out = (float*)d_out;

  char* ws = (char*)d_ws;
  size_t off = 0;
  auto alloc = [&](size_t bytes)->char*{
    char* p = ws + off; off += (bytes + 255) & ~(size_t)255; return p;
  };
  ushort_t* xb    = (ushort_t*)alloc((size_t)M_ROWS * 64 * 2);
  float*    wzT   = (float*)alloc((size_t)2048 * 1024 * 4);
  float*    wot   = (float*)alloc((size_t)1024 * 2048 * 4);
  float*    wht   = (float*)alloc((size_t)64 * 1024 * 4);
  float*    wpT   = (float*)alloc((size_t)1024 * 64 * 4);
  ushort_t* Afold = (ushort_t*)alloc((size_t)128 * 1024 * 2);
  ushort_t* w2tp  = (ushort_t*)alloc((size_t)2432 * 1024 * 2);
  ushort_t* Wcb   = (ushort_t*)alloc((size_t)2432 * 64 * 2);
  float*    bcv   = (float*)alloc((size_t)2432 * 4);
  float*    WdtT  = (float*)alloc((size_t)32 * 64 * 4);
  float*    bcdt  = (float*)alloc((size_t)32 * 4);
  float*    ul    = (float*)alloc((size_t)8 * 1024 * 4);
  ushort_t* xbcBC = (ushort_t*)alloc((size_t)M_ROWS * 256 * 2);
  float*    dtr   = (float*)alloc((size_t)M_ROWS * 32 * 4);
  float*    g     = (float*)alloc((size_t)M_ROWS * 4);
  float*    cfw   = (float*)alloc((size_t)256 * 2048 * 4);
  ushort_t* xhl   = (ushort_t*)alloc((size_t)8 * 2048 * 2);
  float*    yfin  = (float*)alloc((size_t)8 * 2048 * 4);
  float*    zl    = (float*)alloc((size_t)8 * 2048 * 4);
  float*    yn    = (float*)alloc((size_t)8 * 2048 * 4);
  float*    ov    = (float*)alloc((size_t)8 * 1024 * 4);

  k_prep<<<4096 + 512 + 512 + 16 + 16 + 512 + 608 + 64, 256, 0, stream>>>(
      x, w_proj, b_proj, w_in, w_out, w_head, xb, wzT, wot, wht, wpT, Afold, w2tp, yfin);

  k_foldg<<<19 + 32 + 32, 256, 0, stream>>>(Afold, w2tp, Wcb, bcv, xb, w_proj, b_proj, ul,
                                            wpT, w_in, WdtT, bcdt);

  k_gemmBC<<<BC_NB + DTR_NB + ZL_NB, 512, 0, stream>>>(
      xb, Wcb, bcv, xbcBC, WdtT, bcdt, dtr, ul, wzT, zl);

  dim3 gbc(64, 8);
  k_bcg2<<<gbc, 256, 0, stream>>>(xbcBC, conv_w, conv_b, g);

  k_coeff<<<256, 256, 0, stream>>>(dtr, dt_bias, A_log, g, cfw);

  dim3 gx(16, 64);
  k_xsum<<<gx, 512, 0, stream>>>(xb, Wcb, bcv, conv_w, conv_b, cfw, yfin, xhl);

  k_norm<<<8, 256, 0, stream>>>(yfin, xhl, Dp, zl, norm_w, yn);
  k_outproj<<<1024, 64, 0, stream>>>(yn, wot, ov);
  k_head<<<64, 64, 0, stream>>>(ov, wht, b_head, out);
}